// Round 1
// 2172.275 us; speedup vs baseline: 1.3392x; 1.3392x over previous
//
#include <hip/hip_runtime.h>
#include <cstdint>
#include <cstddef>

// ---------- types ----------
typedef float floatx4 __attribute__((ext_vector_type(4)));
typedef __bf16 bf16x8 __attribute__((ext_vector_type(8)));
typedef __attribute__((address_space(3))) unsigned char lds_byte;

__device__ __forceinline__ float bf2f(unsigned short b) {
  union { unsigned int u; float f; } a; a.u = ((unsigned int)b) << 16; return a.f;
}
__device__ __forceinline__ unsigned short f2bf(float f) {
  union { float f; unsigned int u; } a; a.f = f;
  return (unsigned short)((a.u + 0x7fffu + ((a.u >> 16) & 1u)) >> 16);
}

// async global->LDS, 16B per lane, dst = wave-uniform base + lane*16
__device__ __forceinline__ void gld_lds16(const void* g, void* l) {
  __builtin_amdgcn_global_load_lds(
      (const __attribute__((address_space(1))) unsigned int*)g,
      (__attribute__((address_space(3))) unsigned int*)l, 16, 0, 0);
}

// ---------- 128x128 GEMM (m97 structure) for the small (N=1024) GEMMs ----------
template<int OUT_BF16, int ACC>
__global__ __launch_bounds__(256)
void k_gemm_bt(const unsigned short* __restrict__ A,
               const unsigned short* __restrict__ B,
               void* __restrict__ Cv,
               int N, int K) {
  __shared__ unsigned short sA[128 * 32];
  __shared__ unsigned short sB[128 * 32];
  const int tid  = threadIdx.x;
  const int wave = tid >> 6;
  const int lane = tid & 63;
  const int bn = blockIdx.x, bm = blockIdx.y;
  const int wr = wave >> 1, wc = wave & 1;

  floatx4 acc[4][4];
#pragma unroll
  for (int i = 0; i < 4; ++i)
#pragma unroll
    for (int j = 0; j < 4; ++j) acc[i][j] = (floatx4)(0.0f);

  const int srow = (wave << 5) + (lane >> 2);
  const int scol = (lane & 3) << 3;
  const unsigned short* ag = A + (size_t)(bm * 128 + srow) * K + scol;
  const unsigned short* bg = B + (size_t)(bn * 128 + srow) * K + scol;
  unsigned short* lA = sA + (wave << 5) * 32;
  unsigned short* lB = sB + (wave << 5) * 32;
  const size_t rstep = (size_t)16 * K;

  const int aoff = ((wr << 6) + (lane & 15)) * 32 + ((lane >> 4) << 3);
  const int boff = ((wc << 6) + (lane & 15)) * 32 + ((lane >> 4) << 3);

  for (int k0 = 0; k0 < K; k0 += 32) {
    gld_lds16(ag + k0,         lA);
    gld_lds16(ag + k0 + rstep, lA + 512);
    gld_lds16(bg + k0,         lB);
    gld_lds16(bg + k0 + rstep, lB + 512);
    __syncthreads();
    bf16x8 af[4], bf_[4];
#pragma unroll
    for (int i = 0; i < 4; ++i) af[i] = *(const bf16x8*)(sA + aoff + i * 16 * 32);
#pragma unroll
    for (int j = 0; j < 4; ++j) bf_[j] = *(const bf16x8*)(sB + boff + j * 16 * 32);
#pragma unroll
    for (int i = 0; i < 4; ++i)
#pragma unroll
      for (int j = 0; j < 4; ++j)
        acc[i][j] = __builtin_amdgcn_mfma_f32_16x16x32_bf16(af[i], bf_[j], acc[i][j], 0, 0, 0);
    __syncthreads();
  }

  const int crow0 = bm * 128 + (wr << 6) + ((lane >> 4) << 2);
  const int ccol0 = bn * 128 + (wc << 6) + (lane & 15);
#pragma unroll
  for (int i = 0; i < 4; ++i)
#pragma unroll
    for (int r = 0; r < 4; ++r) {
      const size_t row = (size_t)(crow0 + i * 16 + r);
#pragma unroll
      for (int j = 0; j < 4; ++j) {
        const size_t col = (size_t)(ccol0 + j * 16);
        float v = acc[i][j][r];
        if (OUT_BF16) {
          ((unsigned short*)Cv)[row * (size_t)N + col] = f2bf(v);
        } else {
          float* C = (float*)Cv;
          if (ACC) v += C[row * (size_t)N + col];
          C[row * (size_t)N + col] = v;
        }
      }
    }
}

// ---------- 256x256 8-phase GEMM (HK-style schedule, plain HIP) ----------
// A:[M,K] bf16 rm, B:[N,K] bf16 rm. M,N % 256 == 0, K % 64 == 0 (and K/64 >= 2).
// LDS 128 KiB: A dbuf [2][2 half][128][64], B same at +64 KiB.
// Swizzle (involution, bits 7-9 -> bits 4-6): byte ^= ((byte>>7)&7)<<4.
// Staged linearly via global_load_lds with INVERSE-swizzled global source (rule #21).

#define DSR(d, a) asm volatile("ds_read_b128 %0, %1" : "=&v"(d) : "v"(a))

template<int OUT_BF16, int ACC>
__global__ __launch_bounds__(512, 2)
void k_gemm_bt256(const unsigned short* __restrict__ A,
                  const unsigned short* __restrict__ B,
                  void* __restrict__ Cv, int N, int K) {
  __shared__ __align__(16) unsigned short smem[65536];   // 128 KiB
  const int tid = threadIdx.x, wave = tid >> 6, lane = tid & 63;
  const int wr = wave >> 2, wc = wave & 3;               // 2 x 4 wave grid

  // XCD-bijective block swizzle (all our grids have nwg % 8 == 0)
  const unsigned nbx = gridDim.x;
  const unsigned nwg = nbx * gridDim.y;
  unsigned wg = blockIdx.y * nbx + blockIdx.x;
  if ((nwg & 7u) == 0u) wg = (wg & 7u) * (nwg >> 3) + (wg >> 3);
  const int bn = (int)(wg % nbx), bm = (int)(wg / nbx);

  const int NT = K >> 6;

  // ---- staging source coords (inverse-swizzled; f is an involution) ----
  unsigned soff = ((unsigned)tid) << 4;
  soff ^= (((unsigned)tid >> 3) & 7u) << 4;
  const int srow = (int)(soff >> 7);            // 0..63
  const int scol = (int)((soff & 127u) >> 1);   // 0..63 elements
  const size_t Kz = (size_t)K;
  const unsigned short* gA00 = A + ((size_t)(bm * 256 +   0 +  0 + srow)) * Kz + scol;
  const unsigned short* gA01 = A + ((size_t)(bm * 256 +   0 + 64 + srow)) * Kz + scol;
  const unsigned short* gA10 = A + ((size_t)(bm * 256 + 128 +  0 + srow)) * Kz + scol;
  const unsigned short* gA11 = A + ((size_t)(bm * 256 + 128 + 64 + srow)) * Kz + scol;
  const unsigned short* gB00 = B + ((size_t)(bn * 256 +   0 +  0 + srow)) * Kz + scol;
  const unsigned short* gB01 = B + ((size_t)(bn * 256 +   0 + 64 + srow)) * Kz + scol;
  const unsigned short* gB10 = B + ((size_t)(bn * 256 + 128 +  0 + srow)) * Kz + scol;
  const unsigned short* gB11 = B + ((size_t)(bn * 256 + 128 + 64 + srow)) * Kz + scol;

  char* const l0 = (char*)smem;
  const unsigned wb = ((unsigned)wave) << 10;   // wave-uniform lane block (64*16B)
  // LDS byte offsets: A(p,h,tb) = p*32768 + h*16384 + tb*8192; B adds 65536.
#define SA_(P,H,TB,T,GP) gld_lds16((GP) + (size_t)(T) * 64, \
      l0 + (unsigned)((P) * 32768 + (H) * 16384 + (TB) * 8192) + wb)
#define SB_(P,H,TB,T,GP) gld_lds16((GP) + (size_t)(T) * 64, \
      l0 + 65536u + (unsigned)((P) * 32768 + (H) * 16384 + (TB) * 8192) + wb)

  // ---- prologue: tile0 fully, tile1 B + A-top ----
  SB_(0,0,0,0,gB00); SB_(0,0,1,0,gB01); SB_(0,1,0,0,gB10); SB_(0,1,1,0,gB11);
  SA_(0,0,0,0,gA00); SA_(0,1,0,0,gA10); SA_(0,0,1,0,gA01); SA_(0,1,1,0,gA11);
  SB_(1,0,0,1,gB00); SB_(1,0,1,1,gB01); SB_(1,1,0,1,gB10); SB_(1,1,1,1,gB11);
  SA_(1,0,0,1,gA00); SA_(1,1,0,1,gA10);
  asm volatile("s_waitcnt vmcnt(6)" ::: "memory");   // tile0 landed; tile1 (6) in flight
  __builtin_amdgcn_s_barrier();
  __builtin_amdgcn_sched_barrier(0);

  // ---- fragment read offsets (swizzled reads) ----
  lds_byte* lb = (lds_byte*)(void*)smem;
  const unsigned rsw = ((unsigned)(lane & 7)) << 4;
  const unsigned rc0 = ((((unsigned)(lane >> 4)) << 4)) ^ rsw;          // kstep 0
  const unsigned rc1 = (64u + (((unsigned)(lane >> 4)) << 4)) ^ rsw;    // kstep 1
  const unsigned arow = (unsigned)(wr * 16384 + (lane & 15) * 128);
  const unsigned brow = 65536u + (unsigned)((wc >> 1) * 16384 + ((wc & 1) * 64 + (lane & 15)) * 128);

  floatx4 acc[8][4];
#pragma unroll
  for (int i = 0; i < 8; ++i)
#pragma unroll
    for (int j = 0; j < 4; ++j) acc[i][j] = (floatx4)(0.0f);

#define PH_SYNC() do { __builtin_amdgcn_s_barrier(); \
    asm volatile("s_waitcnt lgkmcnt(0)" ::: "memory"); \
    __builtin_amdgcn_sched_barrier(0); } while (0)
#define PH_MFMA(RF) do { \
    __builtin_amdgcn_s_setprio(1); \
    _Pragma("unroll") \
    for (int cf = 0; cf < 4; ++cf) { \
      acc[(RF)][cf]     = __builtin_amdgcn_mfma_f32_16x16x32_bf16(afr[0][0], bfr[cf][0], acc[(RF)][cf],     0, 0, 0); \
      acc[(RF)][cf]     = __builtin_amdgcn_mfma_f32_16x16x32_bf16(afr[0][1], bfr[cf][1], acc[(RF)][cf],     0, 0, 0); \
      acc[(RF) + 1][cf] = __builtin_amdgcn_mfma_f32_16x16x32_bf16(afr[1][0], bfr[cf][0], acc[(RF) + 1][cf], 0, 0, 0); \
      acc[(RF) + 1][cf] = __builtin_amdgcn_mfma_f32_16x16x32_bf16(afr[1][1], bfr[cf][1], acc[(RF) + 1][cf], 0, 0, 0); \
    } \
    __builtin_amdgcn_s_setprio(0); } while (0)
#define PH_DSA(RF) do { \
    DSR(afr[0][0], lb + (ab + (RF) * 2048 + rc0));       DSR(afr[0][1], lb + (ab + (RF) * 2048 + rc1)); \
    DSR(afr[1][0], lb + (ab + ((RF) + 1) * 2048 + rc0)); DSR(afr[1][1], lb + (ab + ((RF) + 1) * 2048 + rc1)); } while (0)

  for (int t = 0; t < NT; ++t) {
    const int pc = t & 1, pn = pc ^ 1;
    const unsigned pb = ((unsigned)pc) << 15;
    const unsigned ab = arow + pb, bb = brow + pb;
    const bool s1 = (t + 1 < NT), s2 = (t + 2 < NT);
    bf16x8 bfr[4][2], afr[2][2];

    // phase 1: all B frags + A rf0-1; stage A-bot(t+1) -> buf pn (idle)
    DSR(bfr[0][0], lb + (bb + 0 * 2048 + rc0)); DSR(bfr[0][1], lb + (bb + 0 * 2048 + rc1));
    DSR(bfr[1][0], lb + (bb + 1 * 2048 + rc0)); DSR(bfr[1][1], lb + (bb + 1 * 2048 + rc1));
    DSR(bfr[2][0], lb + (bb + 2 * 2048 + rc0)); DSR(bfr[2][1], lb + (bb + 2 * 2048 + rc1));
    DSR(bfr[3][0], lb + (bb + 3 * 2048 + rc0)); DSR(bfr[3][1], lb + (bb + 3 * 2048 + rc1));
    PH_DSA(0);
    if (s1) { SA_(pn,0,1,t + 1,gA01); SA_(pn,1,1,t + 1,gA11); }
    PH_SYNC();
    PH_MFMA(0);
    __builtin_amdgcn_s_barrier();

    // phase 2: A rf2-3; stage B-h0(t+2) -> buf pc (B fully consumed in ph1)
    PH_DSA(2);
    if (s2) { SB_(pc,0,0,t + 2,gB00); SB_(pc,0,1,t + 2,gB01); }
    PH_SYNC();
    PH_MFMA(2);
    __builtin_amdgcn_s_barrier();

    // phase 3: A rf4-5; stage B-h1(t+2)
    PH_DSA(4);
    if (s2) { SB_(pc,1,0,t + 2,gB10); SB_(pc,1,1,t + 2,gB11); }
    PH_SYNC();
    PH_MFMA(4);
    __builtin_amdgcn_s_barrier();

    // phase 4: A rf6-7; stage A-top(t+2) (A rows[0,64) consumed by ph2)
    PH_DSA(6);
    if (s2) { SA_(pc,0,0,t + 2,gA00); SA_(pc,1,0,t + 2,gA10); }
    PH_SYNC();
    PH_MFMA(6);
    // tile boundary: counted vmcnt -> tile t+1 landed, 6 loads (t+2) stay in flight
    if (s2) asm volatile("s_waitcnt vmcnt(6)" ::: "memory");
    else    asm volatile("s_waitcnt vmcnt(0)" ::: "memory");
    __builtin_amdgcn_s_barrier();
    __builtin_amdgcn_sched_barrier(0);
  }

  // epilogue: C/D layout col=lane&15, row=(lane>>4)*4+r
  const int crow0 = bm * 256 + wr * 128 + ((lane >> 4) << 2);
  const int ccol0 = bn * 256 + wc * 64 + (lane & 15);
#pragma unroll
  for (int rf = 0; rf < 8; ++rf)
#pragma unroll
    for (int r = 0; r < 4; ++r) {
      const size_t row = (size_t)(crow0 + rf * 16 + r);
#pragma unroll
      for (int cf = 0; cf < 4; ++cf) {
        const size_t col = (size_t)(ccol0 + cf * 16);
        float v = acc[rf][cf][r];
        if (OUT_BF16) {
          ((unsigned short*)Cv)[row * (size_t)N + col] = f2bf(v);
        } else {
          float* C = (float*)Cv;
          if (ACC) v += C[row * (size_t)N + col];
          C[row * (size_t)N + col] = v;
        }
      }
    }
}

// ---------- elementwise kernels ----------
__global__ void k_cvt(const float* __restrict__ x, unsigned short* __restrict__ y, int n4) {
  int i = blockIdx.x * 256 + threadIdx.x;
  if (i >= n4) return;
  float4 v = ((const float4*)x)[i];
  ushort4 o;
  o.x = f2bf(v.x); o.y = f2bf(v.y); o.z = f2bf(v.z); o.w = f2bf(v.w);
  ((ushort4*)y)[i] = o;
}

__global__ void k_cvt_split(const float* __restrict__ x, unsigned short* __restrict__ hi,
                            unsigned short* __restrict__ lo, int n4) {
  int i = blockIdx.x * 256 + threadIdx.x;
  if (i >= n4) return;
  float4 v = ((const float4*)x)[i];
  ushort4 h, l;
  h.x = f2bf(v.x); l.x = f2bf(v.x - bf2f(h.x));
  h.y = f2bf(v.y); l.y = f2bf(v.y - bf2f(h.y));
  h.z = f2bf(v.z); l.z = f2bf(v.z - bf2f(h.z));
  h.w = f2bf(v.w); l.w = f2bf(v.w - bf2f(h.w));
  ((ushort4*)hi)[i] = h;
  ((ushort4*)lo)[i] = l;
}

__global__ void k_build_wbig(const float* __restrict__ lao, const float* __restrict__ fuse,
                             unsigned short* __restrict__ wbig) {
  int idx = blockIdx.x * 256 + threadIdx.x;
  int h = idx >> 10, s = idx & 1023;
  size_t wb = (size_t)h * 7168;
  wbig[wb + s] = f2bf(lao[idx]);
  const float* fp = fuse + (size_t)idx * 6;
#pragma unroll
  for (int g = 0; g < 6; ++g) wbig[wb + 1024 * (g + 1) + s] = f2bf(fp[g]);
}

__global__ void k_build_T(const float* __restrict__ ap, const float* __restrict__ gp,
                          const float* __restrict__ lp, unsigned short* __restrict__ T) {
  int idx = blockIdx.x * 256 + threadIdx.x;
  int s = idx & 1023;
  float a = ap[idx];
  float d = gp[idx] - lp[s];
  size_t base = ((size_t)(idx >> 10)) * 7168 + s;
  T[base] = f2bf(a);
  float p = d;
  T[base + 1024] = f2bf(a * p);
  p *= d * 0.5f;
  T[base + 2048] = f2bf(a * p);
  p *= d * (1.0f / 3.0f);
  T[base + 3072] = f2bf(a * p);
  p *= d * 0.25f;
  T[base + 4096] = f2bf(a * p);
  float keep = (fabsf(d) <= 2.5f) ? 1.0f : 0.0f;
  p *= d * 0.2f;
  T[base + 5120] = f2bf(a * p * keep);
  p *= d * (1.0f / 6.0f);
  T[base + 6144] = f2bf(a * p * keep);
}

__global__ void k_silu_mul(unsigned short* __restrict__ g, const unsigned short* __restrict__ u, int n4) {
  int i = blockIdx.x * 256 + threadIdx.x;
  if (i >= n4) return;
  ushort4 gv = ((const ushort4*)g)[i];
  ushort4 uv = ((const ushort4*)u)[i];
  ushort4 o;
  float x;
  x = bf2f(gv.x); o.x = f2bf(x / (1.0f + expf(-x)) * bf2f(uv.x));
  x = bf2f(gv.y); o.y = f2bf(x / (1.0f + expf(-x)) * bf2f(uv.y));
  x = bf2f(gv.z); o.z = f2bf(x / (1.0f + expf(-x)) * bf2f(uv.z));
  x = bf2f(gv.w); o.w = f2bf(x / (1.0f + expf(-x)) * bf2f(uv.w));
  ((ushort4*)g)[i] = o;
}

// ---------- launch ----------
extern "C" void kernel_launch(void* const* d_in, const int* in_sizes, int n_in,
                              void* d_out, int out_size, void* d_ws, size_t ws_size,
                              hipStream_t stream) {
  const int NR = 4096, H = 4096, S = 1024, F = 9984, KB = 7168;

  const float* x    = (const float*)d_in[0];
  const float* upw  = (const float*)d_in[1];
  const float* gw   = (const float*)d_in[2];
  const float* lp   = (const float*)d_in[3];
  const float* lao  = (const float*)d_in[4];
  const float* fuse = (const float*)d_in[5];
  const float* fgw  = (const float*)d_in[7];
  const float* fuw  = (const float*)d_in[8];
  const float* fdw  = (const float*)d_in[9];
  float* out = (float*)d_out;

  char* ws = (char*)d_ws;
  unsigned short* Xhi  = (unsigned short*)(ws + 0);
  unsigned short* Xlo  = (unsigned short*)(ws + 33554432);
  unsigned short* UPb  = (unsigned short*)(ws + 67108864);
  unsigned short* GWhi = (unsigned short*)(ws + 75497472);
  unsigned short* GWlo = (unsigned short*)(ws + 83886080);
  float*          APf  = (float*)        (ws + 92274688);
  float*          GPf  = (float*)        (ws + 109051904);
  unsigned short* Wbig = (unsigned short*)(ws + 125829120);
  unsigned short* Tbig = (unsigned short*)(ws + 184549376);
  unsigned short* Wf   = (unsigned short*)(ws + 243269632);
  unsigned short* G1   = (unsigned short*)(ws + 325058560);
  unsigned short* U1   = (unsigned short*)(ws + 406847488);

  // conversions
  k_cvt_split<<<(NR * H / 4 + 255) / 256, 256, 0, stream>>>(x, Xhi, Xlo, NR * H / 4);
  k_cvt_split<<<(S * H / 4 + 255) / 256, 256, 0, stream>>>(gw, GWhi, GWlo, S * H / 4);
  k_cvt<<<(S * H / 4 + 255) / 256, 256, 0, stream>>>(upw, UPb, S * H / 4);

  // approx_up = X @ up_w^T (fp32); gate_pre 3-pass hi/lo split (N=1024: keep 128^2 kernel)
  k_gemm_bt<0, 0><<<dim3(S / 128, NR / 128), 256, 0, stream>>>(Xhi, UPb, (void*)APf, S, H);
  k_gemm_bt<0, 0><<<dim3(S / 128, NR / 128), 256, 0, stream>>>(Xhi, GWhi, (void*)GPf, S, H);
  k_gemm_bt<0, 1><<<dim3(S / 128, NR / 128), 256, 0, stream>>>(Xhi, GWlo, (void*)GPf, S, H);
  k_gemm_bt<0, 1><<<dim3(S / 128, NR / 128), 256, 0, stream>>>(Xlo, GWhi, (void*)GPf, S, H);

  // fused Taylor path: out = T_big @ W_big^T  (K = 7168)
  k_build_wbig<<<(H * S + 255) / 256, 256, 0, stream>>>(lao, fuse, Wbig);
  k_build_T<<<(NR * S + 255) / 256, 256, 0, stream>>>(APf, GPf, lp, Tbig);
  k_gemm_bt256<0, 0><<<dim3(H / 256, NR / 256), 512, 0, stream>>>(Tbig, Wbig, (void*)out, H, KB);

  // FFN: out += (silu(X@gw^T) * (X@uw^T)) @ dw^T
  k_cvt<<<(F * H / 4 + 255) / 256, 256, 0, stream>>>(fgw, Wf, F * H / 4);
  k_gemm_bt256<1, 0><<<dim3(F / 256, NR / 256), 512, 0, stream>>>(Xhi, Wf, (void*)G1, F, H);
  k_cvt<<<(F * H / 4 + 255) / 256, 256, 0, stream>>>(fuw, Wf, F * H / 4);
  k_gemm_bt256<1, 0><<<dim3(F / 256, NR / 256), 512, 0, stream>>>(Xhi, Wf, (void*)U1, F, H);
  k_silu_mul<<<(NR * F / 4 + 255) / 256, 256, 0, stream>>>(G1, U1, NR * F / 4);
  k_cvt<<<(H * F / 4 + 255) / 256, 256, 0, stream>>>(fdw, Wf, H * F / 4);
  k_gemm_bt256<0, 1><<<dim3(H / 256, NR / 256), 512, 0, stream>>>(G1, Wf, (void*)out, H, F);
}